// Round 6
// baseline (333.543 us; speedup 1.0000x reference)
//
#include <hip/hip_runtime.h>
#include <math.h>

#define Bsz  4
#define Tlen 4096
#define Cdim 512
#define CUT  (-12.0f)   // neglected-tail std ~6e-4 << absmax budget
#define NBE  8388608    // Bsz*Tlen*Cdim

typedef unsigned int u32;
typedef _Float16 f16;
typedef __attribute__((ext_vector_type(8))) _Float16 f16x8;
typedef __attribute__((ext_vector_type(4))) float floatx4;
#define MFMA_F16(a,b,c) __builtin_amdgcn_mfma_f32_16x16x32_f16((a),(b),(c),0,0,0)

union pun8 { uint4 u; f16x8 f; };

__device__ __forceinline__ u32 pack2(f16 a, f16 b) {
    return (u32)__builtin_bit_cast(unsigned short, a) |
           ((u32)__builtin_bit_cast(unsigned short, b) << 16);
}
__device__ __forceinline__ u32 splitpack(float v) {
    f16 h = (f16)v;
    f16 l = (f16)(v - (float)h);
    return pack2(h, l);
}
// 8 packed (h|l) u32 -> hi f16x8 + lo f16x8 (v_perm_b32)
__device__ __forceinline__ void unpack8(const u32* p, f16x8& h, f16x8& l) {
    uint4 q0 = *(const uint4*)p;
    uint4 q1 = *(const uint4*)(p + 4);
    pun8 ph, pl;
    ph.u.x = __builtin_amdgcn_perm(q0.y, q0.x, 0x05040100u);
    pl.u.x = __builtin_amdgcn_perm(q0.y, q0.x, 0x07060302u);
    ph.u.y = __builtin_amdgcn_perm(q0.w, q0.z, 0x05040100u);
    pl.u.y = __builtin_amdgcn_perm(q0.w, q0.z, 0x07060302u);
    ph.u.z = __builtin_amdgcn_perm(q1.y, q1.x, 0x05040100u);
    pl.u.z = __builtin_amdgcn_perm(q1.y, q1.x, 0x07060302u);
    ph.u.w = __builtin_amdgcn_perm(q1.w, q1.z, 0x05040100u);
    pl.u.w = __builtin_amdgcn_perm(q1.w, q1.z, 0x07060302u);
    h = ph.f; l = pl.f;
}
__device__ __forceinline__ float tanh_fast(float x) {
    return 1.0f - 2.0f / (__expf(2.0f * x) + 1.0f);
}

// ---------------------------------------------------------------------------
// Kernel A (fused prep): blocks 0..2047 = X -> f16; 2048..2239 = W transpose
// -> WT f16 [mat][n][k]; 2240 = gamma scan + decay tables + per-t-tile16 s_lo
// (256 entries, 128-granular s-tiles).
// ---------------------------------------------------------------------------
__global__ __launch_bounds__(256) void prep_kernel(
    const float* __restrict__ X,
    const float* __restrict__ WQ, const float* __restrict__ WK,
    const float* __restrict__ WV,
    f16* __restrict__ Xf, f16* __restrict__ WT,
    float* __restrict__ Lg, float* __restrict__ Wfin, int* __restrict__ sLo) {
    __shared__ char pshm[18432];
    int bid = blockIdx.x, tid = threadIdx.x;
    if (bid < 2048) {
        size_t i = ((size_t)bid * 256 + tid) * 16;
        float v[16];
#pragma unroll
        for (int j = 0; j < 4; ++j) {
            float4 a = *(const float4*)(X + i + j * 4);
            v[j*4+0]=a.x; v[j*4+1]=a.y; v[j*4+2]=a.z; v[j*4+3]=a.w;
        }
        uint4 o0, o1;
        o0.x = pack2((f16)v[0], (f16)v[1]);   o0.y = pack2((f16)v[2], (f16)v[3]);
        o0.z = pack2((f16)v[4], (f16)v[5]);   o0.w = pack2((f16)v[6], (f16)v[7]);
        o1.x = pack2((f16)v[8], (f16)v[9]);   o1.y = pack2((f16)v[10], (f16)v[11]);
        o1.z = pack2((f16)v[12], (f16)v[13]); o1.w = pack2((f16)v[14], (f16)v[15]);
        *(uint4*)(Xf + i) = o0;
        *(uint4*)(Xf + i + 8) = o1;
    } else if (bid < 2240) {
        f16* tile = (f16*)pshm;   // [64][72]
        int wb = bid - 2048;
        int mat = wb >> 6, rem = wb & 63;
        int k0 = (rem >> 3) * 64, n0 = (rem & 7) * 64;
        const float* W = (mat == 0) ? WQ : (mat == 1) ? WK : WV;
        int row = tid >> 2, q = tid & 3;
        const float* src = W + (size_t)(k0 + row) * Cdim + n0 + q * 16;
        float vv[16];
#pragma unroll
        for (int j = 0; j < 4; ++j) {
            float4 v = *(const float4*)(src + j * 4);
            vv[j*4+0]=v.x; vv[j*4+1]=v.y; vv[j*4+2]=v.z; vv[j*4+3]=v.w;
        }
#pragma unroll
        for (int j = 0; j < 16; ++j) tile[(q * 16 + j) * 72 + row] = (f16)vv[j];
        __syncthreads();
        f16x8 r0 = *(const f16x8*)(tile + row * 72 + q * 16);
        f16x8 r1 = *(const f16x8*)(tile + row * 72 + q * 16 + 8);
        f16* dst = WT + ((size_t)mat * Cdim + n0 + row) * Cdim + k0 + q * 16;
        *(f16x8*)dst = r0;
        *(f16x8*)(dst + 8) = r1;
    } else {
        float* Lsh = (float*)pshm;                 // 4097
        float* sums = (float*)(pshm + 16400);      // 256
        float lg[16];
        float local = 0.f;
        int base = tid * 16;
#pragma unroll
        for (int i = 0; i < 16; ++i) {
            int t = base + i;
            float g = 0.96f + 0.03f * ((float)t * (1.0f / 4095.0f));
            lg[i] = logf(g);
            local += lg[i];
        }
        sums[tid] = local;
        __syncthreads();
        for (int off = 1; off < 256; off <<= 1) {
            float v = sums[tid];
            if (tid >= off) v += sums[tid - off];
            __syncthreads();
            sums[tid] = v;
            __syncthreads();
        }
        float pre = (tid == 0) ? 0.f : sums[tid - 1];
#pragma unroll
        for (int i = 0; i < 16; ++i) {
            Lsh[base + i] = pre;
            pre += lg[i];
        }
        if (tid == 255) Lsh[4096] = pre;
        __syncthreads();
        for (int t = tid; t < 4097; t += 256) Lg[t] = Lsh[t];
        float LT = Lsh[4096];
        for (int s = tid; s < 4096; s += 256) Wfin[s] = __expf(LT - Lsh[s + 1]);
        // per-16-row-t-tile s-tile lower bound (256 tiles, 128-granular s)
        {
            float ref = Lsh[tid * 16 + 1];
            int st_hi = tid >> 3;
            int lo = st_hi;
            for (int st = 0; st < st_hi; ++st)
                if (ref - Lsh[st * 128 + 128] > CUT) { lo = st; break; }
            sLo[tid] = lo;
        }
    }
}

// ---------------------------------------------------------------------------
// Kernel B: QKV projection, single-f16 MFMA GEMM, 128x128 tiles, 256 thr
// (4 waves, 64x64 microtile each), LDS-staged kc-chunks of 64 (swizzled).
// Outputs: Qf,Kf row-major f16; KT,VT transposed [b][c][t] f16 written
// coalesced via an LDS transpose bounce.
// ---------------------------------------------------------------------------
__global__ __launch_bounds__(256, 2) void qkv_mfma(
    const f16* __restrict__ Xf, const f16* __restrict__ WT,
    const float* __restrict__ bQ, const float* __restrict__ bK,
    const float* __restrict__ bV,
    f16* __restrict__ Qf, f16* __restrict__ Kf,
    f16* __restrict__ KT, f16* __restrict__ VT) {
    __shared__ char smem[34816];
    u32* sX = (u32*)smem;              // [128][32] words, XOR-swizzled
    u32* sW = (u32*)(smem + 16384);
    f16* sB = (f16*)smem;              // epilogue bounce [128][136] (alias)
    f16* T  = (f16*)smem;              // transpose bounce [128][134] (alias)

    int tid = threadIdx.x, lane = tid & 63, wid = tid >> 6;
    int l16 = lane & 15, quad = lane >> 4;
    int wm = wid & 1, wn = wid >> 1;
    int xb = blockIdx.x;               // 0..11 (mat*4 + n-tile)
    int mat = xb >> 2, n0 = (xb & 3) * 128;
    int m0 = blockIdx.y * 128;

    floatx4 acc[4][4];
#pragma unroll
    for (int i = 0; i < 4; ++i)
#pragma unroll
        for (int j = 0; j < 4; ++j) acc[i][j] = (floatx4)0.f;

    int srow = tid >> 1, shalf = tid & 1;
    int arow_a = wm * 64 + l16, arow_b = wn * 64 + l16;
    int swz_f = (l16 & 7) << 2;

    for (int kc = 0; kc < Cdim; kc += 64) {
        __syncthreads();
        {
            const f16* gx = Xf + (size_t)(m0 + srow) * Cdim + kc + shalf * 32;
            const f16* gw = WT + ((size_t)(mat * Cdim) + n0 + srow) * Cdim + kc + shalf * 32;
            int wswz = (srow & 7) << 2;
#pragma unroll
            for (int k = 0; k < 4; ++k) {
                uint4 xv = *(const uint4*)(gx + k * 8);
                uint4 wv = *(const uint4*)(gw + k * 8);
                int w = shalf * 16 + k * 4;
                *(uint4*)&sX[srow * 32 + (w ^ wswz)] = xv;
                *(uint4*)&sW[srow * 32 + (w ^ wswz)] = wv;
            }
        }
        __syncthreads();
#pragma unroll
        for (int ks = 0; ks < 2; ++ks) {
            int w0 = ks * 16 + quad * 4;
            f16x8 af[4], bf[4];
#pragma unroll
            for (int mt = 0; mt < 4; ++mt)
                af[mt] = ((pun8*)&sX[(arow_a + mt * 16) * 32 + (w0 ^ swz_f)])->f;
#pragma unroll
            for (int nt = 0; nt < 4; ++nt)
                bf[nt] = ((pun8*)&sW[(arow_b + nt * 16) * 32 + (w0 ^ swz_f)])->f;
#pragma unroll
            for (int mt = 0; mt < 4; ++mt)
#pragma unroll
                for (int nt = 0; nt < 4; ++nt)
                    acc[mt][nt] = MFMA_F16(af[mt], bf[nt], acc[mt][nt]);
        }
    }

    const float* bias = (mat == 0) ? bQ : (mat == 1) ? bK : bV;
    float bv[4];
#pragma unroll
    for (int nt = 0; nt < 4; ++nt) bv[nt] = bias[n0 + wn * 64 + nt * 16 + l16];
    float cv[4][4][4];
#pragma unroll
    for (int mt = 0; mt < 4; ++mt)
#pragma unroll
        for (int nt = 0; nt < 4; ++nt)
#pragma unroll
            for (int r = 0; r < 4; ++r) cv[mt][nt][r] = acc[mt][nt][r] + bv[nt];

    int b = m0 >> 12, tloc = m0 & 4095;

    if (mat == 2) {
        // V -> VT via coalescing transpose bounce
        __syncthreads();
#pragma unroll
        for (int mt = 0; mt < 4; ++mt)
#pragma unroll
            for (int nt = 0; nt < 4; ++nt) {
                int dl = wn * 64 + nt * 16 + l16;
                int tl = wm * 64 + mt * 16 + quad * 4;
                *(u32*)(T + dl * 134 + tl)     = pack2((f16)cv[mt][nt][0], (f16)cv[mt][nt][1]);
                *(u32*)(T + dl * 134 + tl + 2) = pack2((f16)cv[mt][nt][2], (f16)cv[mt][nt][3]);
            }
        __syncthreads();
#pragma unroll 8
        for (int dd = 0; dd < 32; ++dd) {
            int dl = wid * 32 + dd;
            u32 v = *(const u32*)(T + dl * 134 + lane * 2);
            *(u32*)(VT + ((size_t)(b * Cdim + n0 + dl)) * Tlen + tloc + lane * 2) = v;
        }
    } else {
        // row-major via LDS bounce (Qf / Kf)
        __syncthreads();
#pragma unroll
        for (int mt = 0; mt < 4; ++mt)
#pragma unroll
            for (int nt = 0; nt < 4; ++nt)
#pragma unroll
                for (int r = 0; r < 4; ++r)
                    sB[(wm * 64 + mt * 16 + quad * 4 + r) * 136 +
                       wn * 64 + nt * 16 + l16] = (f16)cv[mt][nt][r];
        __syncthreads();
        {
            f16* Out = (mat == 0) ? Qf : Kf;
            int r2 = tid >> 1, h2 = tid & 1;
            f16* dst = Out + (size_t)(m0 + r2) * Cdim + n0 + h2 * 64;
#pragma unroll
            for (int j = 0; j < 8; ++j)
                *(uint4*)(dst + j * 8) = *(const uint4*)(sB + r2 * 136 + h2 * 64 + j * 8);
        }
        if (mat == 1) {
            // K -> KT via coalescing transpose bounce
            __syncthreads();
#pragma unroll
            for (int mt = 0; mt < 4; ++mt)
#pragma unroll
                for (int nt = 0; nt < 4; ++nt) {
                    int dl = wn * 64 + nt * 16 + l16;
                    int tl = wm * 64 + mt * 16 + quad * 4;
                    *(u32*)(T + dl * 134 + tl)     = pack2((f16)cv[mt][nt][0], (f16)cv[mt][nt][1]);
                    *(u32*)(T + dl * 134 + tl + 2) = pack2((f16)cv[mt][nt][2], (f16)cv[mt][nt][3]);
                }
            __syncthreads();
#pragma unroll 8
            for (int dd = 0; dd < 32; ++dd) {
                int dl = wid * 32 + dd;
                u32 v = *(const u32*)(T + dl * 134 + lane * 2);
                *(u32*)(KT + ((size_t)(b * Cdim + n0 + dl)) * Tlen + tloc + lane * 2) = v;
            }
        }
    }
}

// ---------------------------------------------------------------------------
// Kernel C: attention v5. Same proven per-iteration dataflow as R1/R5, but
// t-tile = 16 rows -> 1024 blocks, LDS 24.8 KB -> 4 blocks/CU resident
// (32 waves/CU nominal): barrier drains of one block overlap the other 3
// independent blocks; tail granularity 2x finer. Per-wave per-iteration
// load counts identical (K 16x16B, V 16x16B); MFMA/iter halves, iters 2x.
// Phase1: wave owns 16-wide s-strip (K read 1x); phase2: wave owns 64-wide
// d-strip (V read 1x). Q staged once in swizzled LDS; P transits LDS packed
// h|l u32 (proven swizzle). 2 barriers per s-tile.
// ---------------------------------------------------------------------------
__global__ __launch_bounds__(512, 8) void attn_mfma(
    const f16* __restrict__ Qf, const f16* __restrict__ Kf,
    const f16* __restrict__ VT, const float* __restrict__ Lg,
    const int* __restrict__ sLo, float* __restrict__ out) {
    __shared__ char smem[24832];
    u32* sQ = (u32*)smem;             // [16][256] words (16 KB)
    u32* sP = (u32*)(smem + 16384);   // [16][132] words (8.45 KB)

    int tid = threadIdx.x, lane = tid & 63, wid = tid >> 6;
    int l16 = lane & 15, quad = lane >> 4;

    int i = blockIdx.x;
    int halfsel = i >> 9, q = i & 511;
    int L = ((q & 7) << 6) | (q >> 3);   // XCD-major: xcd k gets 64 contiguous tiles
    int b = L >> 7, ttl = L & 127;
    int tt = halfsel ? (127 - ttl) : (128 + ttl);
    int t0 = tt * 16;
    size_t bT = (size_t)b * Tlen;
    int lo = sLo[tt], hi = tt >> 3;

    // ---- stage Q tile (16 rows x 512 f16) into swizzled LDS
    {
        int r = tid >> 5, c = tid & 31;
        const f16* src = Qf + (bT + t0 + r) * Cdim + c * 16;
        int wswz = (r & 7) << 2;
#pragma unroll
        for (int k = 0; k < 2; ++k) {
            uint4 v = *(const uint4*)(src + k * 8);
            int w = c * 8 + k * 4;
            *(uint4*)&sQ[r * 256 + (w ^ wswz)] = v;
        }
    }

    float aT[4];
#pragma unroll
    for (int r = 0; r < 4; ++r)
        aT[r] = Lg[t0 + quad * 4 + r + 1];

    floatx4 oacc[4];
#pragma unroll
    for (int nt = 0; nt < 4; ++nt) oacc[nt] = (floatx4)0.f;

    int swz_f = (l16 & 7) << 2;
    int rowA0 = l16 * 256;

    __syncthreads();

    for (int st = lo; st <= hi; ++st) {
        int s0 = st * 128;
        float lsp = Lg[s0 + wid * 16 + l16 + 1];

        floatx4 pacc = (floatx4)0.f;

        // ---- phase 1: P = Q . K^T  (Q from LDS, K direct global, no dup)
        const f16* kb = Kf + (bT + s0 + wid * 16 + l16) * Cdim;
#pragma unroll 4
        for (int kc = 0; kc < 16; ++kc) {
            int ko = kc * 32 + quad * 8;
            int w0 = kc * 16 + quad * 4;
            f16x8 a0 = ((pun8*)&sQ[rowA0 + (w0 ^ swz_f)])->f;
            f16x8 bk = *(const f16x8*)(kb + ko);
            pacc = MFMA_F16(a0, bk, pacc);
        }

        // ---- weight + mask + split into LDS
        __syncthreads();   // prior phase2 done reading sP
#pragma unroll
        for (int r = 0; r < 4; ++r) {
            int tl = quad * 4 + r;
            int sl = wid * 16 + l16;
            int t = t0 + tl, s = s0 + sl;
            float p = pacc[r];
            p = (s <= t) ? p * __expf(aT[r] - lsp) : 0.f;
            sP[tl * 132 + (sl ^ ((tl & 7) << 4))] = splitpack(p);
        }
        __syncthreads();

        // ---- phase 2: O += (Ph+Pl) . V  (P from LDS, V direct global, no dup)
        const f16* vb = VT + ((size_t)(b * Cdim + wid * 64 + l16)) * Tlen + s0;
#pragma unroll
        for (int kf = 0; kf < 4; ++kf) {
            int sb = kf * 32 + quad * 8;
            f16x8 ph, pl;
            unpack8(&sP[l16 * 132 + (sb ^ ((l16 & 7) << 4))], ph, pl);
#pragma unroll
            for (int nt = 0; nt < 4; ++nt) {
                f16x8 vf = *(const f16x8*)(vb + (size_t)nt * 16 * Tlen + sb);
                oacc[nt] = MFMA_F16(ph, vf, oacc[nt]);
                oacc[nt] = MFMA_F16(pl, vf, oacc[nt]);
            }
        }
    }

    // ---- epilogue: fused tanh + direct store
#pragma unroll
    for (int nt = 0; nt < 4; ++nt)
#pragma unroll
        for (int r = 0; r < 4; ++r) {
            int t = t0 + quad * 4 + r;
            int d = wid * 64 + nt * 16 + l16;
            out[(bT + t) * (size_t)Cdim + d] = tanh_fast(oacc[nt][r]);
        }
}

// ---------------------------------------------------------------------------
// Kernel D: S_final = sum_s Wfin[s] * K[s]^T V[s] via f16 MFMA on KT/VT.
// 64c x 128d tiles -> grid (8,4,4) = 128 blocks.
// ---------------------------------------------------------------------------
__global__ __launch_bounds__(256) void sfinal_mfma(
    const f16* __restrict__ KT, const f16* __restrict__ VT,
    const float* __restrict__ Lg, const float* __restrict__ Wfin,
    float* __restrict__ S) {
    __shared__ f16 sA[64 * 72];     // weighted K^T chunk [64c][64s]
    __shared__ f16 sB2[128 * 72];   // V^T chunk [128d][64s]
    int tid = threadIdx.x, lane = tid & 63, wid = tid >> 6;
    int l16 = lane & 15, quad = lane >> 4;
    int wv_c = wid >> 1, wv_d = wid & 1;
    int c0 = blockIdx.x * 64, d0 = blockIdx.y * 128, bb = blockIdx.z;
    float LT = Lg[Tlen];
    floatx4 acc[2][4];
#pragma unroll
    for (int i = 0; i < 2; ++i)
#pragma unroll
        for (int jj = 0; jj < 4; ++jj) acc[i][jj] = (floatx4)0.f;

    int s0start = Tlen - 64;
    for (int s0 = 0; s0 < Tlen; s0 += 64)
        if (LT - Lg[s0 + 64] > CUT) { s0start = s0; break; }

    int rowA = tid >> 2, qA = (tid & 3) * 16;    // 64 rows x 16 f16
    int rowB = tid >> 1, qB = (tid & 1) * 32;    // 128 rows x 32 f16
    for (int s0 = s0start; s0 < Tlen; s0 += 64) {
        __syncthreads();
        {
            const f16* g = KT + ((size_t)(bb * Cdim + c0 + rowA)) * Tlen + s0 + qA;
            f16x8 u0 = *(const f16x8*)g;
            f16x8 u1 = *(const f16x8*)(g + 8);
            float wv[16];
#pragma unroll
            for (int jj = 0; jj < 4; ++jj) {
                float4 w4 = *(const float4*)(Wfin + s0 + qA + jj * 4);
                wv[jj*4+0]=w4.x; wv[jj*4+1]=w4.y; wv[jj*4+2]=w4.z; wv[jj*4+3]=w4.w;
            }
            f16x8 o0, o1;
#pragma unroll
            for (int jj = 0; jj < 8; ++jj) o0[jj] = (f16)((float)u0[jj] * wv[jj]);
#pragma unroll
            for (int jj = 0; jj < 8; ++jj) o1[jj] = (f16)((float)u1[jj] * wv[8 + jj]);
            *(f16x8*)(sA + rowA * 72 + qA) = o0;
            *(f16x8*)(sA + rowA * 72 + qA + 8) = o1;
            const f16* gv = VT + ((size_t)(bb * Cdim + d0 + rowB)) * Tlen + s0 + qB;
#pragma unroll
            for (int jj = 0; jj < 4; ++jj)
                *(uint4*)(sB2 + rowB * 72 + qB + jj * 8) = *(const uint4*)(gv + jj * 8);
        }
        __syncthreads();
#pragma unroll
        for (int ks = 0; ks < 2; ++ks) {
            int ko = ks * 32 + quad * 8;
            f16x8 av[2], bv2[4];
#pragma unroll
            for (int ct = 0; ct < 2; ++ct)
                av[ct] = *(const f16x8*)(sA + (wv_c * 32 + ct * 16 + l16) * 72 + ko);
#pragma unroll
            for (int dt = 0; dt < 4; ++dt)
                bv2[dt] = *(const f16x8*)(sB2 + (wv_d * 64 + dt * 16 + l16) * 72 + ko);
#pragma unroll
            for (int ct = 0; ct < 2; ++ct)
#pragma unroll
                for (int dt = 0; dt < 4; ++dt)
                    acc[ct][dt] = MFMA_F16(av[ct], bv2[dt], acc[ct][dt]);
        }
    }
#pragma unroll
    for (int ct = 0; ct < 2; ++ct)
#pragma unroll
        for (int dt = 0; dt < 4; ++dt)
#pragma unroll
            for (int r = 0; r < 4; ++r) {
                int c = c0 + wv_c * 32 + ct * 16 + quad * 4 + r;
                int d = d0 + wv_d * 64 + dt * 16 + l16;
                S[((size_t)(bb * Cdim + c)) * Cdim + d] = acc[ct][dt][r];
            }
}

// ---------------------------------------------------------------------------
extern "C" void kernel_launch(void* const* d_in, const int* in_sizes, int n_in,
                              void* d_out, int out_size, void* d_ws, size_t ws_size,
                              hipStream_t stream) {
    (void)in_sizes; (void)n_in; (void)out_size; (void)ws_size;
    const float* X  = (const float*)d_in[0];
    const float* WQ = (const float*)d_in[2];
    const float* bQ = (const float*)d_in[3];
    const float* WK = (const float*)d_in[4];
    const float* bK = (const float*)d_in[5];
    const float* WV = (const float*)d_in[6];
    const float* bV = (const float*)d_in[7];

    float* out   = (float*)d_out;
    float* S_out = out + (size_t)NBE;

    char* ws = (char*)d_ws;
    f16*   Xf   = (f16*)(ws);                       // 2*NBE bytes each
    f16*   Qf   = (f16*)(ws + 2ull * NBE);
    f16*   Kf   = (f16*)(ws + 4ull * NBE);
    f16*   KT   = (f16*)(ws + 6ull * NBE);
    f16*   VT   = (f16*)(ws + 8ull * NBE);
    f16*   WT   = (f16*)(ws + 10ull * NBE);         // 1.5 MB
    char*  tail = ws + 10ull * NBE + (2u << 20);
    float* Lg   = (float*)(tail);                   // 4097
    float* Wfin = (float*)(tail + 16512);           // 4096
    int*   sLo  = (int*)(tail + 16512 + 16384);     // 256

    prep_kernel<<<2241, 256, 0, stream>>>(X, WQ, WK, WV, Xf, WT, Lg, Wfin, sLo);
    qkv_mfma<<<dim3(12, 128), 256, 0, stream>>>(Xf, WT, bQ, bK, bV, Qf, Kf, KT, VT);
    attn_mfma<<<1024, 512, 0, stream>>>(Qf, Kf, VT, Lg, sLo, out);
    sfinal_mfma<<<dim3(8, 4, Bsz), 256, 0, stream>>>(KT, VT, Lg, Wfin, S_out);
}

// Round 7
// 291.965 us; speedup vs baseline: 1.1424x; 1.1424x over previous
//
#include <hip/hip_runtime.h>
#include <math.h>

#define Bsz  4
#define Tlen 4096
#define Cdim 512
#define CUT  (-12.0f)   // neglected-tail std ~6e-4 << absmax budget
#define NBE  8388608    // Bsz*Tlen*Cdim

typedef unsigned int u32;
typedef _Float16 f16;
typedef __attribute__((ext_vector_type(8))) _Float16 f16x8;
typedef __attribute__((ext_vector_type(4))) float floatx4;
#define MFMA_F16(a,b,c) __builtin_amdgcn_mfma_f32_16x16x32_f16((a),(b),(c),0,0,0)

union pun8 { uint4 u; f16x8 f; };

__device__ __forceinline__ u32 pack2(f16 a, f16 b) {
    return (u32)__builtin_bit_cast(unsigned short, a) |
           ((u32)__builtin_bit_cast(unsigned short, b) << 16);
}
__device__ __forceinline__ u32 splitpack(float v) {
    f16 h = (f16)v;
    f16 l = (f16)(v - (float)h);
    return pack2(h, l);
}
// 8 packed (h|l) u32 -> hi f16x8 + lo f16x8 (v_perm_b32)
__device__ __forceinline__ void unpack8(const u32* p, f16x8& h, f16x8& l) {
    uint4 q0 = *(const uint4*)p;
    uint4 q1 = *(const uint4*)(p + 4);
    pun8 ph, pl;
    ph.u.x = __builtin_amdgcn_perm(q0.y, q0.x, 0x05040100u);
    pl.u.x = __builtin_amdgcn_perm(q0.y, q0.x, 0x07060302u);
    ph.u.y = __builtin_amdgcn_perm(q0.w, q0.z, 0x05040100u);
    pl.u.y = __builtin_amdgcn_perm(q0.w, q0.z, 0x07060302u);
    ph.u.z = __builtin_amdgcn_perm(q1.y, q1.x, 0x05040100u);
    pl.u.z = __builtin_amdgcn_perm(q1.y, q1.x, 0x07060302u);
    ph.u.w = __builtin_amdgcn_perm(q1.w, q1.z, 0x05040100u);
    pl.u.w = __builtin_amdgcn_perm(q1.w, q1.z, 0x07060302u);
    h = ph.f; l = pl.f;
}
__device__ __forceinline__ float tanh_fast(float x) {
    return 1.0f - 2.0f / (__expf(2.0f * x) + 1.0f);
}

// ---------------------------------------------------------------------------
// Kernel A (fused prep): blocks 0..2047 = X -> f16; 2048..2239 = W transpose
// -> WT f16 [mat][n][k]; 2240 = gamma scan + decay tables + per-t-tile32 s_lo
// (128-granular s-tiles, matching attn).  [R5-proven, verbatim]
// ---------------------------------------------------------------------------
__global__ __launch_bounds__(256) void prep_kernel(
    const float* __restrict__ X,
    const float* __restrict__ WQ, const float* __restrict__ WK,
    const float* __restrict__ WV,
    f16* __restrict__ Xf, f16* __restrict__ WT,
    float* __restrict__ Lg, float* __restrict__ Wfin, int* __restrict__ sLo) {
    __shared__ char pshm[18432];
    int bid = blockIdx.x, tid = threadIdx.x;
    if (bid < 2048) {
        size_t i = ((size_t)bid * 256 + tid) * 16;
        float v[16];
#pragma unroll
        for (int j = 0; j < 4; ++j) {
            float4 a = *(const float4*)(X + i + j * 4);
            v[j*4+0]=a.x; v[j*4+1]=a.y; v[j*4+2]=a.z; v[j*4+3]=a.w;
        }
        uint4 o0, o1;
        o0.x = pack2((f16)v[0], (f16)v[1]);   o0.y = pack2((f16)v[2], (f16)v[3]);
        o0.z = pack2((f16)v[4], (f16)v[5]);   o0.w = pack2((f16)v[6], (f16)v[7]);
        o1.x = pack2((f16)v[8], (f16)v[9]);   o1.y = pack2((f16)v[10], (f16)v[11]);
        o1.z = pack2((f16)v[12], (f16)v[13]); o1.w = pack2((f16)v[14], (f16)v[15]);
        *(uint4*)(Xf + i) = o0;
        *(uint4*)(Xf + i + 8) = o1;
    } else if (bid < 2240) {
        f16* tile = (f16*)pshm;   // [64][72]
        int wb = bid - 2048;
        int mat = wb >> 6, rem = wb & 63;
        int k0 = (rem >> 3) * 64, n0 = (rem & 7) * 64;
        const float* W = (mat == 0) ? WQ : (mat == 1) ? WK : WV;
        int row = tid >> 2, q = tid & 3;
        const float* src = W + (size_t)(k0 + row) * Cdim + n0 + q * 16;
        float vv[16];
#pragma unroll
        for (int j = 0; j < 4; ++j) {
            float4 v = *(const float4*)(src + j * 4);
            vv[j*4+0]=v.x; vv[j*4+1]=v.y; vv[j*4+2]=v.z; vv[j*4+3]=v.w;
        }
#pragma unroll
        for (int j = 0; j < 16; ++j) tile[(q * 16 + j) * 72 + row] = (f16)vv[j];
        __syncthreads();
        f16x8 r0 = *(const f16x8*)(tile + row * 72 + q * 16);
        f16x8 r1 = *(const f16x8*)(tile + row * 72 + q * 16 + 8);
        f16* dst = WT + ((size_t)mat * Cdim + n0 + row) * Cdim + k0 + q * 16;
        *(f16x8*)dst = r0;
        *(f16x8*)(dst + 8) = r1;
    } else {
        float* Lsh = (float*)pshm;                 // 4097
        float* sums = (float*)(pshm + 16400);      // 256
        float lg[16];
        float local = 0.f;
        int base = tid * 16;
#pragma unroll
        for (int i = 0; i < 16; ++i) {
            int t = base + i;
            float g = 0.96f + 0.03f * ((float)t * (1.0f / 4095.0f));
            lg[i] = logf(g);
            local += lg[i];
        }
        sums[tid] = local;
        __syncthreads();
        for (int off = 1; off < 256; off <<= 1) {
            float v = sums[tid];
            if (tid >= off) v += sums[tid - off];
            __syncthreads();
            sums[tid] = v;
            __syncthreads();
        }
        float pre = (tid == 0) ? 0.f : sums[tid - 1];
#pragma unroll
        for (int i = 0; i < 16; ++i) {
            Lsh[base + i] = pre;
            pre += lg[i];
        }
        if (tid == 255) Lsh[4096] = pre;
        __syncthreads();
        for (int t = tid; t < 4097; t += 256) Lg[t] = Lsh[t];
        float LT = Lsh[4096];
        for (int s = tid; s < 4096; s += 256) Wfin[s] = __expf(LT - Lsh[s + 1]);
        // per-32-row-t-tile s-tile lower bound (128-granular s-tiles)
        if (tid < 128) {
            float ref = Lsh[tid * 32 + 1];
            int st_hi = tid >> 2;
            int lo = st_hi;
            for (int st = 0; st < st_hi; ++st)
                if (ref - Lsh[st * 128 + 128] > CUT) { lo = st; break; }
            sLo[tid] = lo;
        }
    }
}

// ---------------------------------------------------------------------------
// Kernel B: QKV projection, single-f16 MFMA GEMM, 128x128 tiles, 256 thr
// (4 waves, 64x64 microtile each), LDS-staged kc-chunks of 64 (swizzled).
// v2: X-chunk REGISTER PREFETCH (next chunk's 4x uint4 issued before the
// MFMA barrier -> latency hides under 32 MFMAs + 2 barriers; +16 VGPR only,
// stays under the 128 cap). KT output DELETED (sfinal now reads Kf).
// Outputs: Qf,Kf row-major f16; VT transposed [b][c][t] f16 (coalesced via
// LDS transpose bounce).
// ---------------------------------------------------------------------------
__global__ __launch_bounds__(256, 2) void qkv_mfma(
    const f16* __restrict__ Xf, const f16* __restrict__ WT,
    const float* __restrict__ bQ, const float* __restrict__ bK,
    const float* __restrict__ bV,
    f16* __restrict__ Qf, f16* __restrict__ Kf,
    f16* __restrict__ VT) {
    __shared__ char smem[34816];
    u32* sX = (u32*)smem;              // [128][32] words, XOR-swizzled
    u32* sW = (u32*)(smem + 16384);
    f16* sB = (f16*)smem;              // epilogue bounce [128][136] (alias)
    f16* T  = (f16*)smem;              // transpose bounce [128][134] (alias)

    int tid = threadIdx.x, lane = tid & 63, wid = tid >> 6;
    int l16 = lane & 15, quad = lane >> 4;
    int wm = wid & 1, wn = wid >> 1;
    int xb = blockIdx.x;               // 0..11 (mat*4 + n-tile)
    int mat = xb >> 2, n0 = (xb & 3) * 128;
    int m0 = blockIdx.y * 128;

    floatx4 acc[4][4];
#pragma unroll
    for (int i = 0; i < 4; ++i)
#pragma unroll
        for (int j = 0; j < 4; ++j) acc[i][j] = (floatx4)0.f;

    int srow = tid >> 1, shalf = tid & 1;
    int arow_a = wm * 64 + l16, arow_b = wn * 64 + l16;
    int swz_f = (l16 & 7) << 2;
    int wswz = (srow & 7) << 2;

    const f16* gx_base = Xf + (size_t)(m0 + srow) * Cdim + shalf * 32;
    const f16* gw_base = WT + ((size_t)(mat * Cdim) + n0 + srow) * Cdim + shalf * 32;

    // ---- prologue: prefetch X chunk 0 into registers
    uint4 px[4];
#pragma unroll
    for (int k = 0; k < 4; ++k) px[k] = *(const uint4*)(gx_base + k * 8);

    for (int kc = 0; kc < Cdim; kc += 64) {
        __syncthreads();
        {
#pragma unroll
            for (int k = 0; k < 4; ++k) {
                uint4 wv = *(const uint4*)(gw_base + kc + k * 8);
                int w = shalf * 16 + k * 4;
                *(uint4*)&sX[srow * 32 + (w ^ wswz)] = px[k];
                *(uint4*)&sW[srow * 32 + (w ^ wswz)] = wv;
            }
            if (kc + 64 < Cdim) {
#pragma unroll
                for (int k = 0; k < 4; ++k)
                    px[k] = *(const uint4*)(gx_base + kc + 64 + k * 8);
            }
        }
        __syncthreads();
#pragma unroll
        for (int ks = 0; ks < 2; ++ks) {
            int w0 = ks * 16 + quad * 4;
            f16x8 af[4], bf[4];
#pragma unroll
            for (int mt = 0; mt < 4; ++mt)
                af[mt] = ((pun8*)&sX[(arow_a + mt * 16) * 32 + (w0 ^ swz_f)])->f;
#pragma unroll
            for (int nt = 0; nt < 4; ++nt)
                bf[nt] = ((pun8*)&sW[(arow_b + nt * 16) * 32 + (w0 ^ swz_f)])->f;
#pragma unroll
            for (int mt = 0; mt < 4; ++mt)
#pragma unroll
                for (int nt = 0; nt < 4; ++nt)
                    acc[mt][nt] = MFMA_F16(af[mt], bf[nt], acc[mt][nt]);
        }
    }

    const float* bias = (mat == 0) ? bQ : (mat == 1) ? bK : bV;
    float bv[4];
#pragma unroll
    for (int nt = 0; nt < 4; ++nt) bv[nt] = bias[n0 + wn * 64 + nt * 16 + l16];
    float cv[4][4][4];
#pragma unroll
    for (int mt = 0; mt < 4; ++mt)
#pragma unroll
        for (int nt = 0; nt < 4; ++nt)
#pragma unroll
            for (int r = 0; r < 4; ++r) cv[mt][nt][r] = acc[mt][nt][r] + bv[nt];

    int b = m0 >> 12, tloc = m0 & 4095;

    if (mat == 2) {
        // V -> VT via coalescing transpose bounce
        __syncthreads();
#pragma unroll
        for (int mt = 0; mt < 4; ++mt)
#pragma unroll
            for (int nt = 0; nt < 4; ++nt) {
                int dl = wn * 64 + nt * 16 + l16;
                int tl = wm * 64 + mt * 16 + quad * 4;
                *(u32*)(T + dl * 134 + tl)     = pack2((f16)cv[mt][nt][0], (f16)cv[mt][nt][1]);
                *(u32*)(T + dl * 134 + tl + 2) = pack2((f16)cv[mt][nt][2], (f16)cv[mt][nt][3]);
            }
        __syncthreads();
#pragma unroll 8
        for (int dd = 0; dd < 32; ++dd) {
            int dl = wid * 32 + dd;
            u32 v = *(const u32*)(T + dl * 134 + lane * 2);
            *(u32*)(VT + ((size_t)(b * Cdim + n0 + dl)) * Tlen + tloc + lane * 2) = v;
        }
    } else {
        // row-major via LDS bounce (Qf / Kf)
        __syncthreads();
#pragma unroll
        for (int mt = 0; mt < 4; ++mt)
#pragma unroll
            for (int nt = 0; nt < 4; ++nt)
#pragma unroll
                for (int r = 0; r < 4; ++r)
                    sB[(wm * 64 + mt * 16 + quad * 4 + r) * 136 +
                       wn * 64 + nt * 16 + l16] = (f16)cv[mt][nt][r];
        __syncthreads();
        {
            f16* Out = (mat == 0) ? Qf : Kf;
            int r2 = tid >> 1, h2 = tid & 1;
            f16* dst = Out + (size_t)(m0 + r2) * Cdim + n0 + h2 * 64;
#pragma unroll
            for (int j = 0; j < 8; ++j)
                *(uint4*)(dst + j * 8) = *(const uint4*)(sB + r2 * 136 + h2 * 64 + j * 8);
        }
    }
}

// ---------------------------------------------------------------------------
// Kernel C: attention (R1/R5-proven structure, verbatim). t-tile = 32 rows ->
// 512 tiles, grid 512 = 2 blocks/CU. Long/short complement pairing + XCD-
// major mapping. Phase1: wave owns 16-wide s-strip (K read 1x); phase2:
// wave owns 64-wide d-strip (V read 1x). Q staged once in swizzled LDS;
// P transits LDS packed h|l u32. 2 barriers per s-tile.
// ---------------------------------------------------------------------------
__global__ __launch_bounds__(512, 4) void attn_mfma(
    const f16* __restrict__ Qf, const f16* __restrict__ Kf,
    const f16* __restrict__ VT, const float* __restrict__ Lg,
    const int* __restrict__ sLo, float* __restrict__ out) {
    __shared__ char smem[49664];
    u32* sQ  = (u32*)smem;             // [32][256] words (32 KB)
    u32* sPc = (u32*)(smem + 32768);   // [32][132]  (16.9 KB)

    int tid = threadIdx.x, lane = tid & 63, wid = tid >> 6;
    int l16 = lane & 15, quad = lane >> 4;

    int i = blockIdx.x;
    int halfsel = i >> 8, q = i & 255;
    int L = ((q & 7) << 5) | (q >> 3);   // XCD-major: xcd k gets 32 contiguous tiles
    int b = L >> 6, ttl = L & 63;
    int tt = halfsel ? (63 - ttl) : (64 + ttl);
    int t0 = tt * 32;
    size_t bT = (size_t)b * Tlen;
    int lo = sLo[tt], hi = tt >> 2;

    // ---- stage Q tile (32 rows x 512 f16) into swizzled LDS
    {
        int r = tid >> 4, c16 = tid & 15;
        const f16* src = Qf + (bT + t0 + r) * Cdim + c16 * 32;
        int wswz = (r & 7) << 2;
#pragma unroll
        for (int k = 0; k < 4; ++k) {
            uint4 v = *(const uint4*)(src + k * 8);
            int w = c16 * 16 + k * 4;
            *(uint4*)&sQ[r * 256 + (w ^ wswz)] = v;
        }
    }

    float aT[2][4];
#pragma unroll
    for (int mt = 0; mt < 2; ++mt)
#pragma unroll
        for (int r = 0; r < 4; ++r)
            aT[mt][r] = Lg[t0 + mt * 16 + quad * 4 + r + 1];

    floatx4 oacc[2][4];
#pragma unroll
    for (int mt = 0; mt < 2; ++mt)
#pragma unroll
        for (int nt = 0; nt < 4; ++nt) oacc[mt][nt] = (floatx4)0.f;

    int swz_f = (l16 & 7) << 2;
    int rowA0 = l16 * 256;
    int rowA1 = (16 + l16) * 256;

    __syncthreads();

    for (int st = lo; st <= hi; ++st) {
        int s0 = st * 128;
        float lsp = Lg[s0 + wid * 16 + l16 + 1];

        floatx4 pacc[2];
        pacc[0] = (floatx4)0.f; pacc[1] = (floatx4)0.f;

        // ---- phase 1: P = Q . K^T  (Q from LDS, K direct global, no dup)
        const f16* kb = Kf + (bT + s0 + wid * 16 + l16) * Cdim;
#pragma unroll 4
        for (int kc = 0; kc < 16; ++kc) {
            int ko = kc * 32 + quad * 8;
            int w0 = kc * 16 + quad * 4;
            f16x8 a0 = ((pun8*)&sQ[rowA0 + (w0 ^ swz_f)])->f;
            f16x8 a1 = ((pun8*)&sQ[rowA1 + (w0 ^ swz_f)])->f;
            f16x8 bk = *(const f16x8*)(kb + ko);
            pacc[0] = MFMA_F16(a0, bk, pacc[0]);
            pacc[1] = MFMA_F16(a1, bk, pacc[1]);
        }

        // ---- weight + mask + split into LDS
        __syncthreads();   // prior phase2 done reading sPc
#pragma unroll
        for (int mt = 0; mt < 2; ++mt)
#pragma unroll
            for (int r = 0; r < 4; ++r) {
                int tl = mt * 16 + quad * 4 + r;
                int sl = wid * 16 + l16;
                int t = t0 + tl, s = s0 + sl;
                float p = pacc[mt][r];
                p = (s <= t) ? p * __expf(aT[mt][r] - lsp) : 0.f;
                sPc[tl * 132 + (sl ^ ((tl & 7) << 4))] = splitpack(p);
            }
        __syncthreads();

        // ---- phase 2: O += (Ph+Pl) . V  (P from LDS, V direct global, no dup)
        const f16* vb = VT + ((size_t)(b * Cdim + wid * 64 + l16)) * Tlen + s0;
#pragma unroll
        for (int kf = 0; kf < 4; ++kf) {
            int sb = kf * 32 + quad * 8;
            f16x8 ph[2], pl[2];
#pragma unroll
            for (int mt = 0; mt < 2; ++mt) {
                int tl = mt * 16 + l16;
                unpack8(&sPc[tl * 132 + (sb ^ ((tl & 7) << 4))], ph[mt], pl[mt]);
            }
#pragma unroll
            for (int nt = 0; nt < 4; ++nt) {
                f16x8 vf = *(const f16x8*)(vb + (size_t)nt * 16 * Tlen + sb);
#pragma unroll
                for (int mt = 0; mt < 2; ++mt) {
                    oacc[mt][nt] = MFMA_F16(ph[mt], vf, oacc[mt][nt]);
                    oacc[mt][nt] = MFMA_F16(pl[mt], vf, oacc[mt][nt]);
                }
            }
        }
    }

    // ---- epilogue: fused tanh + direct store
#pragma unroll
    for (int mt = 0; mt < 2; ++mt)
#pragma unroll
        for (int nt = 0; nt < 4; ++nt)
#pragma unroll
            for (int r = 0; r < 4; ++r) {
                int t = t0 + mt * 16 + quad * 4 + r;
                int d = wid * 64 + nt * 16 + l16;
                out[(bT + t) * (size_t)Cdim + d] = tanh_fast(oacc[mt][nt][r]);
            }
}

// ---------------------------------------------------------------------------
// Kernel D: S_final = sum_s Wfin[s] * K[s]^T V[s] via f16 MFMA. v2: K read
// from row-major Kf (KT buffer deleted); weight+transpose applied during LDS
// staging (prep W-transpose pattern). 64x64 tiles, grid (8,8,4) = 256 blocks
// -> full GPU (the 128-block R5 grid left half the CUs idle).
// ---------------------------------------------------------------------------
__global__ __launch_bounds__(256) void sfinal_mfma(
    const f16* __restrict__ Kf, const f16* __restrict__ VT,
    const float* __restrict__ Lg, const float* __restrict__ Wfin,
    float* __restrict__ S) {
    __shared__ f16 sA[64 * 72];     // weighted K^T chunk [64c][64s]
    __shared__ f16 sB2[64 * 72];    // V^T chunk [64d][64s]
    int tid = threadIdx.x, lane = tid & 63, wid = tid >> 6;
    int l16 = lane & 15, quad = lane >> 4;
    int wv_c = wid & 1, wv_d = wid >> 1;
    int c0 = blockIdx.x * 64, d0 = blockIdx.y * 64, bb = blockIdx.z;
    float LT = Lg[Tlen];
    floatx4 acc[2][2];
#pragma unroll
    for (int i = 0; i < 2; ++i)
#pragma unroll
        for (int jj = 0; jj < 2; ++jj) acc[i][jj] = (floatx4)0.f;

    int s0start = Tlen - 64;
    for (int s0 = 0; s0 < Tlen; s0 += 64)
        if (LT - Lg[s0 + 64] > CUT) { s0start = s0; break; }

    int rowS = tid >> 2, q = tid & 3;
    for (int s0 = s0start; s0 < Tlen; s0 += 64) {
        __syncthreads();
        {
            // K: row s0+rowS, cols c0+q*16..+16 -> weighted, transposed store
            const f16* gk = Kf + ((size_t)(bb * Tlen + s0 + rowS)) * Cdim + c0 + q * 16;
            f16x8 k0 = *(const f16x8*)gk;
            f16x8 k1 = *(const f16x8*)(gk + 8);
            float w = Wfin[s0 + rowS];
#pragma unroll
            for (int j = 0; j < 8; ++j)
                sA[(q * 16 + j) * 72 + rowS] = (f16)((float)k0[j] * w);
#pragma unroll
            for (int j = 0; j < 8; ++j)
                sA[(q * 16 + 8 + j) * 72 + rowS] = (f16)((float)k1[j] * w);
            // V: VT[d][s] rows direct
            const f16* gv = VT + ((size_t)(bb * Cdim + d0 + rowS)) * Tlen + s0 + q * 16;
            *(uint4*)(sB2 + rowS * 72 + q * 16) = *(const uint4*)gv;
            *(uint4*)(sB2 + rowS * 72 + q * 16 + 8) = *(const uint4*)(gv + 8);
        }
        __syncthreads();
#pragma unroll
        for (int ks = 0; ks < 2; ++ks) {
            int ko = ks * 32 + quad * 8;
            f16x8 a0 = *(const f16x8*)(sA + (wv_c * 32 + l16) * 72 + ko);
            f16x8 a1 = *(const f16x8*)(sA + (wv_c * 32 + 16 + l16) * 72 + ko);
            f16x8 b0 = *(const f16x8*)(sB2 + (wv_d * 32 + l16) * 72 + ko);
            f16x8 b1 = *(const f16x8*)(sB2 + (wv_d * 32 + 16 + l16) * 72 + ko);
            acc[0][0] = MFMA_F16(a0, b0, acc[0][0]);
            acc[0][1] = MFMA_F16(a0, b1, acc[0][1]);
            acc[1][0] = MFMA_F16(a1, b0, acc[1][0]);
            acc[1][1] = MFMA_F16(a1, b1, acc[1][1]);
        }
    }
#pragma unroll
    for (int ct = 0; ct < 2; ++ct)
#pragma unroll
        for (int dt = 0; dt < 2; ++dt)
#pragma unroll
            for (int r = 0; r < 4; ++r) {
                int c = c0 + wv_c * 32 + ct * 16 + quad * 4 + r;
                int d = d0 + wv_d * 32 + dt * 16 + l16;
                S[((size_t)(bb * Cdim + c)) * Cdim + d] = acc[ct][dt][r];
            }
}

// ---------------------------------------------------------------------------
extern "C" void kernel_launch(void* const* d_in, const int* in_sizes, int n_in,
                              void* d_out, int out_size, void* d_ws, size_t ws_size,
                              hipStream_t stream) {
    (void)in_sizes; (void)n_in; (void)out_size; (void)ws_size;
    const float* X  = (const float*)d_in[0];
    const float* WQ = (const float*)d_in[2];
    const float* bQ = (const float*)d_in[3];
    const float* WK = (const float*)d_in[4];
    const float* bK = (const float*)d_in[5];
    const float* WV = (const float*)d_in[6];
    const float* bV = (const float*)d_in[7];

    float* out   = (float*)d_out;
    float* S_out = out + (size_t)NBE;

    char* ws = (char*)d_ws;
    f16*   Xf   = (f16*)(ws);                       // 2*NBE bytes each
    f16*   Qf   = (f16*)(ws + 2ull * NBE);
    f16*   Kf   = (f16*)(ws + 4ull * NBE);
    f16*   VT   = (f16*)(ws + 6ull * NBE);
    f16*   WT   = (f16*)(ws + 8ull * NBE);          // 1.5 MB
    char*  tail = ws + 8ull * NBE + (2u << 20);
    float* Lg   = (float*)(tail);                   // 4097
    float* Wfin = (float*)(tail + 16512);           // 4096
    int*   sLo  = (int*)(tail + 16512 + 16384);     // 128

    prep_kernel<<<2241, 256, 0, stream>>>(X, WQ, WK, WV, Xf, WT, Lg, Wfin, sLo);
    qkv_mfma<<<dim3(12, 128), 256, 0, stream>>>(Xf, WT, bQ, bK, bV, Qf, Kf, VT);
    attn_mfma<<<512, 512, 0, stream>>>(Qf, Kf, VT, Lg, sLo, out);
    sfinal_mfma<<<dim3(8, 8, Bsz), 256, 0, stream>>>(Kf, VT, Lg, Wfin, S_out);
}

// Round 8
// 260.355 us; speedup vs baseline: 1.2811x; 1.1214x over previous
//
#include <hip/hip_runtime.h>
#include <math.h>

#define Bsz  4
#define Tlen 4096
#define Cdim 512
#define CUT  (-12.0f)   // neglected-tail std ~6e-4 << absmax budget
#define NBE  8388608    // Bsz*Tlen*Cdim

typedef unsigned int u32;
typedef _Float16 f16;
typedef __attribute__((ext_vector_type(8))) _Float16 f16x8;
typedef __attribute__((ext_vector_type(4))) float floatx4;
#define MFMA_F16(a,b,c) __builtin_amdgcn_mfma_f32_16x16x32_f16((a),(b),(c),0,0,0)

union pun8 { uint4 u; f16x8 f; };

__device__ __forceinline__ u32 pack2(f16 a, f16 b) {
    return (u32)__builtin_bit_cast(unsigned short, a) |
           ((u32)__builtin_bit_cast(unsigned short, b) << 16);
}
__device__ __forceinline__ u32 splitpack(float v) {
    f16 h = (f16)v;
    f16 l = (f16)(v - (float)h);
    return pack2(h, l);
}
// 8 packed (h|l) u32 -> hi f16x8 + lo f16x8 (v_perm_b32)
__device__ __forceinline__ void unpack8(const u32* p, f16x8& h, f16x8& l) {
    uint4 q0 = *(const uint4*)p;
    uint4 q1 = *(const uint4*)(p + 4);
    pun8 ph, pl;
    ph.u.x = __builtin_amdgcn_perm(q0.y, q0.x, 0x05040100u);
    pl.u.x = __builtin_amdgcn_perm(q0.y, q0.x, 0x07060302u);
    ph.u.y = __builtin_amdgcn_perm(q0.w, q0.z, 0x05040100u);
    pl.u.y = __builtin_amdgcn_perm(q0.w, q0.z, 0x07060302u);
    ph.u.z = __builtin_amdgcn_perm(q1.y, q1.x, 0x05040100u);
    pl.u.z = __builtin_amdgcn_perm(q1.y, q1.x, 0x07060302u);
    ph.u.w = __builtin_amdgcn_perm(q1.w, q1.z, 0x05040100u);
    pl.u.w = __builtin_amdgcn_perm(q1.w, q1.z, 0x07060302u);
    h = ph.f; l = pl.f;
}
__device__ __forceinline__ float tanh_fast(float x) {
    return 1.0f - 2.0f / (__expf(2.0f * x) + 1.0f);
}

// ---------------------------------------------------------------------------
// Kernel A (fused prep): blocks 0..2047 = X -> f16; 2048..2239 = W transpose
// -> WT f16 [mat][n][k]; 2240 = gamma scan + decay tables + per-t-tile32 s_lo
// (128-granular s-tiles, matching attn).  [R5-proven, verbatim]
// ---------------------------------------------------------------------------
__global__ __launch_bounds__(256) void prep_kernel(
    const float* __restrict__ X,
    const float* __restrict__ WQ, const float* __restrict__ WK,
    const float* __restrict__ WV,
    f16* __restrict__ Xf, f16* __restrict__ WT,
    float* __restrict__ Lg, float* __restrict__ Wfin, int* __restrict__ sLo) {
    __shared__ char pshm[18432];
    int bid = blockIdx.x, tid = threadIdx.x;
    if (bid < 2048) {
        size_t i = ((size_t)bid * 256 + tid) * 16;
        float v[16];
#pragma unroll
        for (int j = 0; j < 4; ++j) {
            float4 a = *(const float4*)(X + i + j * 4);
            v[j*4+0]=a.x; v[j*4+1]=a.y; v[j*4+2]=a.z; v[j*4+3]=a.w;
        }
        uint4 o0, o1;
        o0.x = pack2((f16)v[0], (f16)v[1]);   o0.y = pack2((f16)v[2], (f16)v[3]);
        o0.z = pack2((f16)v[4], (f16)v[5]);   o0.w = pack2((f16)v[6], (f16)v[7]);
        o1.x = pack2((f16)v[8], (f16)v[9]);   o1.y = pack2((f16)v[10], (f16)v[11]);
        o1.z = pack2((f16)v[12], (f16)v[13]); o1.w = pack2((f16)v[14], (f16)v[15]);
        *(uint4*)(Xf + i) = o0;
        *(uint4*)(Xf + i + 8) = o1;
    } else if (bid < 2240) {
        f16* tile = (f16*)pshm;   // [64][72]
        int wb = bid - 2048;
        int mat = wb >> 6, rem = wb & 63;
        int k0 = (rem >> 3) * 64, n0 = (rem & 7) * 64;
        const float* W = (mat == 0) ? WQ : (mat == 1) ? WK : WV;
        int row = tid >> 2, q = tid & 3;
        const float* src = W + (size_t)(k0 + row) * Cdim + n0 + q * 16;
        float vv[16];
#pragma unroll
        for (int j = 0; j < 4; ++j) {
            float4 v = *(const float4*)(src + j * 4);
            vv[j*4+0]=v.x; vv[j*4+1]=v.y; vv[j*4+2]=v.z; vv[j*4+3]=v.w;
        }
#pragma unroll
        for (int j = 0; j < 16; ++j) tile[(q * 16 + j) * 72 + row] = (f16)vv[j];
        __syncthreads();
        f16x8 r0 = *(const f16x8*)(tile + row * 72 + q * 16);
        f16x8 r1 = *(const f16x8*)(tile + row * 72 + q * 16 + 8);
        f16* dst = WT + ((size_t)mat * Cdim + n0 + row) * Cdim + k0 + q * 16;
        *(f16x8*)dst = r0;
        *(f16x8*)(dst + 8) = r1;
    } else {
        float* Lsh = (float*)pshm;                 // 4097
        float* sums = (float*)(pshm + 16400);      // 256
        float lg[16];
        float local = 0.f;
        int base = tid * 16;
#pragma unroll
        for (int i = 0; i < 16; ++i) {
            int t = base + i;
            float g = 0.96f + 0.03f * ((float)t * (1.0f / 4095.0f));
            lg[i] = logf(g);
            local += lg[i];
        }
        sums[tid] = local;
        __syncthreads();
        for (int off = 1; off < 256; off <<= 1) {
            float v = sums[tid];
            if (tid >= off) v += sums[tid - off];
            __syncthreads();
            sums[tid] = v;
            __syncthreads();
        }
        float pre = (tid == 0) ? 0.f : sums[tid - 1];
#pragma unroll
        for (int i = 0; i < 16; ++i) {
            Lsh[base + i] = pre;
            pre += lg[i];
        }
        if (tid == 255) Lsh[4096] = pre;
        __syncthreads();
        for (int t = tid; t < 4097; t += 256) Lg[t] = Lsh[t];
        float LT = Lsh[4096];
        for (int s = tid; s < 4096; s += 256) Wfin[s] = __expf(LT - Lsh[s + 1]);
        // per-32-row-t-tile s-tile lower bound (128-granular s-tiles)
        if (tid < 128) {
            float ref = Lsh[tid * 32 + 1];
            int st_hi = tid >> 2;
            int lo = st_hi;
            for (int st = 0; st < st_hi; ++st)
                if (ref - Lsh[st * 128 + 128] > CUT) { lo = st; break; }
            sLo[tid] = lo;
        }
    }
}

// ---------------------------------------------------------------------------
// Kernel B: QKV projection, single-f16 MFMA GEMM, 128x128 tiles, 256 thr
// (4 waves, 64x64 microtile each), LDS-staged kc-chunks of 64 (swizzled).
// v3: XCD-GROUPED 1-D GRID (1536 blocks). flat -> xcd=flat&7, rem=flat>>3;
// m_idx = xcd*16 + rem/12, x_idx = rem%12 (bijective). All 12 (mat,n-tile)
// blocks sharing one Xf row-tile carry ids == same value mod 8 -> same XCD,
// dispatched within a 96-id window -> tile fetched from HBM once, 11/12
// reads served by that XCD's private L2 (~5 concurrent tiles x 128 KB << 4
// MB; WT 1.5 MB stays L2-hot). Pure index remap.
// Outputs: Qf,Kf row-major f16; KT,VT transposed [b][c][t] f16 via
// coalescing LDS transpose bounce.
// ---------------------------------------------------------------------------
__global__ __launch_bounds__(256, 2) void qkv_mfma(
    const f16* __restrict__ Xf, const f16* __restrict__ WT,
    const float* __restrict__ bQ, const float* __restrict__ bK,
    const float* __restrict__ bV,
    f16* __restrict__ Qf, f16* __restrict__ Kf,
    f16* __restrict__ KT, f16* __restrict__ VT) {
    __shared__ char smem[34816];
    u32* sX = (u32*)smem;              // [128][32] words, XOR-swizzled
    u32* sW = (u32*)(smem + 16384);
    f16* sB = (f16*)smem;              // epilogue bounce [128][136] (alias)
    f16* T  = (f16*)smem;              // transpose bounce [128][134] (alias)

    int tid = threadIdx.x, lane = tid & 63, wid = tid >> 6;
    int l16 = lane & 15, quad = lane >> 4;
    int wm = wid & 1, wn = wid >> 1;

    int flat = blockIdx.x;             // 0..1535
    int xcd = flat & 7, rem = flat >> 3;      // rem 0..191
    int m_idx = xcd * 16 + rem / 12;          // 0..127
    int x_idx = rem % 12;                     // 0..11
    int mat = x_idx >> 2, n0 = (x_idx & 3) * 128;
    int m0 = m_idx * 128;

    floatx4 acc[4][4];
#pragma unroll
    for (int i = 0; i < 4; ++i)
#pragma unroll
        for (int j = 0; j < 4; ++j) acc[i][j] = (floatx4)0.f;

    int srow = tid >> 1, shalf = tid & 1;
    int arow_a = wm * 64 + l16, arow_b = wn * 64 + l16;
    int swz_f = (l16 & 7) << 2;

    for (int kc = 0; kc < Cdim; kc += 64) {
        __syncthreads();
        {
            const f16* gx = Xf + (size_t)(m0 + srow) * Cdim + kc + shalf * 32;
            const f16* gw = WT + ((size_t)(mat * Cdim) + n0 + srow) * Cdim + kc + shalf * 32;
            int wswz = (srow & 7) << 2;
#pragma unroll
            for (int k = 0; k < 4; ++k) {
                uint4 xv = *(const uint4*)(gx + k * 8);
                uint4 wv = *(const uint4*)(gw + k * 8);
                int w = shalf * 16 + k * 4;
                *(uint4*)&sX[srow * 32 + (w ^ wswz)] = xv;
                *(uint4*)&sW[srow * 32 + (w ^ wswz)] = wv;
            }
        }
        __syncthreads();
#pragma unroll
        for (int ks = 0; ks < 2; ++ks) {
            int w0 = ks * 16 + quad * 4;
            f16x8 af[4], bf[4];
#pragma unroll
            for (int mt = 0; mt < 4; ++mt)
                af[mt] = ((pun8*)&sX[(arow_a + mt * 16) * 32 + (w0 ^ swz_f)])->f;
#pragma unroll
            for (int nt = 0; nt < 4; ++nt)
                bf[nt] = ((pun8*)&sW[(arow_b + nt * 16) * 32 + (w0 ^ swz_f)])->f;
#pragma unroll
            for (int mt = 0; mt < 4; ++mt)
#pragma unroll
                for (int nt = 0; nt < 4; ++nt)
                    acc[mt][nt] = MFMA_F16(af[mt], bf[nt], acc[mt][nt]);
        }
    }

    const float* bias = (mat == 0) ? bQ : (mat == 1) ? bK : bV;
    float bv[4];
#pragma unroll
    for (int nt = 0; nt < 4; ++nt) bv[nt] = bias[n0 + wn * 64 + nt * 16 + l16];
    float cv[4][4][4];
#pragma unroll
    for (int mt = 0; mt < 4; ++mt)
#pragma unroll
        for (int nt = 0; nt < 4; ++nt)
#pragma unroll
            for (int r = 0; r < 4; ++r) cv[mt][nt][r] = acc[mt][nt][r] + bv[nt];

    int b = m0 >> 12, tloc = m0 & 4095;

    if (mat == 2) {
        // V -> VT via coalescing transpose bounce
        __syncthreads();
#pragma unroll
        for (int mt = 0; mt < 4; ++mt)
#pragma unroll
            for (int nt = 0; nt < 4; ++nt) {
                int dl = wn * 64 + nt * 16 + l16;
                int tl = wm * 64 + mt * 16 + quad * 4;
                *(u32*)(T + dl * 134 + tl)     = pack2((f16)cv[mt][nt][0], (f16)cv[mt][nt][1]);
                *(u32*)(T + dl * 134 + tl + 2) = pack2((f16)cv[mt][nt][2], (f16)cv[mt][nt][3]);
            }
        __syncthreads();
#pragma unroll 8
        for (int dd = 0; dd < 32; ++dd) {
            int dl = wid * 32 + dd;
            u32 v = *(const u32*)(T + dl * 134 + lane * 2);
            *(u32*)(VT + ((size_t)(b * Cdim + n0 + dl)) * Tlen + tloc + lane * 2) = v;
        }
    } else {
        // row-major via LDS bounce (Qf / Kf)
        __syncthreads();
#pragma unroll
        for (int mt = 0; mt < 4; ++mt)
#pragma unroll
            for (int nt = 0; nt < 4; ++nt)
#pragma unroll
                for (int r = 0; r < 4; ++r)
                    sB[(wm * 64 + mt * 16 + quad * 4 + r) * 136 +
                       wn * 64 + nt * 16 + l16] = (f16)cv[mt][nt][r];
        __syncthreads();
        {
            f16* Out = (mat == 0) ? Qf : Kf;
            int r2 = tid >> 1, h2 = tid & 1;
            f16* dst = Out + (size_t)(m0 + r2) * Cdim + n0 + h2 * 64;
#pragma unroll
            for (int j = 0; j < 8; ++j)
                *(uint4*)(dst + j * 8) = *(const uint4*)(sB + r2 * 136 + h2 * 64 + j * 8);
        }
        if (mat == 1) {
            // K -> KT via coalescing transpose bounce
            __syncthreads();
#pragma unroll
            for (int mt = 0; mt < 4; ++mt)
#pragma unroll
                for (int nt = 0; nt < 4; ++nt) {
                    int dl = wn * 64 + nt * 16 + l16;
                    int tl = wm * 64 + mt * 16 + quad * 4;
                    *(u32*)(T + dl * 134 + tl)     = pack2((f16)cv[mt][nt][0], (f16)cv[mt][nt][1]);
                    *(u32*)(T + dl * 134 + tl + 2) = pack2((f16)cv[mt][nt][2], (f16)cv[mt][nt][3]);
                }
            __syncthreads();
#pragma unroll 8
            for (int dd = 0; dd < 32; ++dd) {
                int dl = wid * 32 + dd;
                u32 v = *(const u32*)(T + dl * 134 + lane * 2);
                *(u32*)(KT + ((size_t)(b * Cdim + n0 + dl)) * Tlen + tloc + lane * 2) = v;
            }
        }
    }
}

// ---------------------------------------------------------------------------
// Kernel C: attention (R1/R5-proven structure, verbatim). t-tile = 32 rows ->
// 512 tiles, grid 512 = 2 blocks/CU. Long/short complement pairing + XCD-
// major mapping. Phase1: wave owns 16-wide s-strip (K read 1x); phase2:
// wave owns 64-wide d-strip (V read 1x). Q staged once in swizzled LDS;
// P transits LDS packed h|l u32. 2 barriers per s-tile.
// ---------------------------------------------------------------------------
__global__ __launch_bounds__(512, 4) void attn_mfma(
    const f16* __restrict__ Qf, const f16* __restrict__ Kf,
    const f16* __restrict__ VT, const float* __restrict__ Lg,
    const int* __restrict__ sLo, float* __restrict__ out) {
    __shared__ char smem[49664];
    u32* sQ  = (u32*)smem;             // [32][256] words (32 KB)
    u32* sPc = (u32*)(smem + 32768);   // [32][132]  (16.9 KB)

    int tid = threadIdx.x, lane = tid & 63, wid = tid >> 6;
    int l16 = lane & 15, quad = lane >> 4;

    int i = blockIdx.x;
    int halfsel = i >> 8, q = i & 255;
    int L = ((q & 7) << 5) | (q >> 3);   // XCD-major: xcd k gets 32 contiguous tiles
    int b = L >> 6, ttl = L & 63;
    int tt = halfsel ? (63 - ttl) : (64 + ttl);
    int t0 = tt * 32;
    size_t bT = (size_t)b * Tlen;
    int lo = sLo[tt], hi = tt >> 2;

    // ---- stage Q tile (32 rows x 512 f16) into swizzled LDS
    {
        int r = tid >> 4, c16 = tid & 15;
        const f16* src = Qf + (bT + t0 + r) * Cdim + c16 * 32;
        int wswz = (r & 7) << 2;
#pragma unroll
        for (int k = 0; k < 4; ++k) {
            uint4 v = *(const uint4*)(src + k * 8);
            int w = c16 * 16 + k * 4;
            *(uint4*)&sQ[r * 256 + (w ^ wswz)] = v;
        }
    }

    float aT[2][4];
#pragma unroll
    for (int mt = 0; mt < 2; ++mt)
#pragma unroll
        for (int r = 0; r < 4; ++r)
            aT[mt][r] = Lg[t0 + mt * 16 + quad * 4 + r + 1];

    floatx4 oacc[2][4];
#pragma unroll
    for (int mt = 0; mt < 2; ++mt)
#pragma unroll
        for (int nt = 0; nt < 4; ++nt) oacc[mt][nt] = (floatx4)0.f;

    int swz_f = (l16 & 7) << 2;
    int rowA0 = l16 * 256;
    int rowA1 = (16 + l16) * 256;

    __syncthreads();

    for (int st = lo; st <= hi; ++st) {
        int s0 = st * 128;
        float lsp = Lg[s0 + wid * 16 + l16 + 1];

        floatx4 pacc[2];
        pacc[0] = (floatx4)0.f; pacc[1] = (floatx4)0.f;

        // ---- phase 1: P = Q . K^T  (Q from LDS, K direct global, no dup)
        const f16* kb = Kf + (bT + s0 + wid * 16 + l16) * Cdim;
#pragma unroll 4
        for (int kc = 0; kc < 16; ++kc) {
            int ko = kc * 32 + quad * 8;
            int w0 = kc * 16 + quad * 4;
            f16x8 a0 = ((pun8*)&sQ[rowA0 + (w0 ^ swz_f)])->f;
            f16x8 a1 = ((pun8*)&sQ[rowA1 + (w0 ^ swz_f)])->f;
            f16x8 bk = *(const f16x8*)(kb + ko);
            pacc[0] = MFMA_F16(a0, bk, pacc[0]);
            pacc[1] = MFMA_F16(a1, bk, pacc[1]);
        }

        // ---- weight + mask + split into LDS
        __syncthreads();   // prior phase2 done reading sPc
#pragma unroll
        for (int mt = 0; mt < 2; ++mt)
#pragma unroll
            for (int r = 0; r < 4; ++r) {
                int tl = mt * 16 + quad * 4 + r;
                int sl = wid * 16 + l16;
                int t = t0 + tl, s = s0 + sl;
                float p = pacc[mt][r];
                p = (s <= t) ? p * __expf(aT[mt][r] - lsp) : 0.f;
                sPc[tl * 132 + (sl ^ ((tl & 7) << 4))] = splitpack(p);
            }
        __syncthreads();

        // ---- phase 2: O += (Ph+Pl) . V  (P from LDS, V direct global, no dup)
        const f16* vb = VT + ((size_t)(b * Cdim + wid * 64 + l16)) * Tlen + s0;
#pragma unroll
        for (int kf = 0; kf < 4; ++kf) {
            int sb = kf * 32 + quad * 8;
            f16x8 ph[2], pl[2];
#pragma unroll
            for (int mt = 0; mt < 2; ++mt) {
                int tl = mt * 16 + l16;
                unpack8(&sPc[tl * 132 + (sb ^ ((tl & 7) << 4))], ph[mt], pl[mt]);
            }
#pragma unroll
            for (int nt = 0; nt < 4; ++nt) {
                f16x8 vf = *(const f16x8*)(vb + (size_t)nt * 16 * Tlen + sb);
#pragma unroll
                for (int mt = 0; mt < 2; ++mt) {
                    oacc[mt][nt] = MFMA_F16(ph[mt], vf, oacc[mt][nt]);
                    oacc[mt][nt] = MFMA_F16(pl[mt], vf, oacc[mt][nt]);
                }
            }
        }
    }

    // ---- epilogue: fused tanh + direct store
#pragma unroll
    for (int mt = 0; mt < 2; ++mt)
#pragma unroll
        for (int nt = 0; nt < 4; ++nt)
#pragma unroll
            for (int r = 0; r < 4; ++r) {
                int t = t0 + mt * 16 + quad * 4 + r;
                int d = wid * 64 + nt * 16 + l16;
                out[(bT + t) * (size_t)Cdim + d] = tanh_fast(oacc[mt][nt][r]);
            }
}

// ---------------------------------------------------------------------------
// Kernel D: S_final = sum_s Wfin[s] * K[s]^T V[s] via f16 MFMA on KT/VT.
// 64c x 128d tiles -> grid (8,4,4) = 128 blocks.  [R5-proven, verbatim]
// ---------------------------------------------------------------------------
__global__ __launch_bounds__(256) void sfinal_mfma(
    const f16* __restrict__ KT, const f16* __restrict__ VT,
    const float* __restrict__ Lg, const float* __restrict__ Wfin,
    float* __restrict__ S) {
    __shared__ f16 sA[64 * 72];     // weighted K^T chunk [64c][64s]
    __shared__ f16 sB2[128 * 72];   // V^T chunk [128d][64s]
    int tid = threadIdx.x, lane = tid & 63, wid = tid >> 6;
    int l16 = lane & 15, quad = lane >> 4;
    int wv_c = wid >> 1, wv_d = wid & 1;
    int c0 = blockIdx.x * 64, d0 = blockIdx.y * 128, bb = blockIdx.z;
    float LT = Lg[Tlen];
    floatx4 acc[2][4];
#pragma unroll
    for (int i = 0; i < 2; ++i)
#pragma unroll
        for (int jj = 0; jj < 4; ++jj) acc[i][jj] = (floatx4)0.f;

    int s0start = Tlen - 64;
    for (int s0 = 0; s0 < Tlen; s0 += 64)
        if (LT - Lg[s0 + 64] > CUT) { s0start = s0; break; }

    int rowA = tid >> 2, qA = (tid & 3) * 16;    // 64 rows x 16 f16
    int rowB = tid >> 1, qB = (tid & 1) * 32;    // 128 rows x 32 f16
    for (int s0 = s0start; s0 < Tlen; s0 += 64) {
        __syncthreads();
        {
            const f16* g = KT + ((size_t)(bb * Cdim + c0 + rowA)) * Tlen + s0 + qA;
            f16x8 u0 = *(const f16x8*)g;
            f16x8 u1 = *(const f16x8*)(g + 8);
            float wv[16];
#pragma unroll
            for (int jj = 0; jj < 4; ++jj) {
                float4 w4 = *(const float4*)(Wfin + s0 + qA + jj * 4);
                wv[jj*4+0]=w4.x; wv[jj*4+1]=w4.y; wv[jj*4+2]=w4.z; wv[jj*4+3]=w4.w;
            }
            f16x8 o0, o1;
#pragma unroll
            for (int jj = 0; jj < 8; ++jj) o0[jj] = (f16)((float)u0[jj] * wv[jj]);
#pragma unroll
            for (int jj = 0; jj < 8; ++jj) o1[jj] = (f16)((float)u1[jj] * wv[8 + jj]);
            *(f16x8*)(sA + rowA * 72 + qA) = o0;
            *(f16x8*)(sA + rowA * 72 + qA + 8) = o1;
            const f16* gv = VT + ((size_t)(bb * Cdim + d0 + rowB)) * Tlen + s0 + qB;
#pragma unroll
            for (int jj = 0; jj < 4; ++jj)
                *(uint4*)(sB2 + rowB * 72 + qB + jj * 8) = *(const uint4*)(gv + jj * 8);
        }
        __syncthreads();
#pragma unroll
        for (int ks = 0; ks < 2; ++ks) {
            int ko = ks * 32 + quad * 8;
            f16x8 av[2], bv2[4];
#pragma unroll
            for (int ct = 0; ct < 2; ++ct)
                av[ct] = *(const f16x8*)(sA + (wv_c * 32 + ct * 16 + l16) * 72 + ko);
#pragma unroll
            for (int dt = 0; dt < 4; ++dt)
                bv2[dt] = *(const f16x8*)(sB2 + (wv_d * 64 + dt * 16 + l16) * 72 + ko);
#pragma unroll
            for (int ct = 0; ct < 2; ++ct)
#pragma unroll
                for (int dt = 0; dt < 4; ++dt)
                    acc[ct][dt] = MFMA_F16(av[ct], bv2[dt], acc[ct][dt]);
        }
    }
#pragma unroll
    for (int ct = 0; ct < 2; ++ct)
#pragma unroll
        for (int dt = 0; dt < 4; ++dt)
#pragma unroll
            for (int r = 0; r < 4; ++r) {
                int c = c0 + wv_c * 32 + ct * 16 + quad * 4 + r;
                int d = d0 + wv_d * 64 + dt * 16 + l16;
                S[((size_t)(bb * Cdim + c)) * Cdim + d] = acc[ct][dt][r];
            }
}

// ---------------------------------------------------------------------------
extern "C" void kernel_launch(void* const* d_in, const int* in_sizes, int n_in,
                              void* d_out, int out_size, void* d_ws, size_t ws_size,
                              hipStream_t stream) {
    (void)in_sizes; (void)n_in; (void)out_size; (void)ws_size;
    const float* X  = (const float*)d_in[0];
    const float* WQ = (const float*)d_in[2];
    const float* bQ = (const float*)d_in[3];
    const float* WK = (const float*)d_in[4];
    const float* bK = (const float*)d_in[5];
    const float* WV = (const float*)d_in[6];
    const float* bV = (const float*)d_in[7];

    float* out   = (float*)d_out;
    float* S_out = out + (size_t)NBE;

    char* ws = (char*)d_ws;
    f16*   Xf   = (f16*)(ws);                       // 2*NBE bytes each
    f16*   Qf   = (f16*)(ws + 2ull * NBE);
    f16*   Kf   = (f16*)(ws + 4ull * NBE);
    f16*   KT   = (f16*)(ws + 6ull * NBE);
    f16*   VT   = (f16*)(ws + 8ull * NBE);
    f16*   WT   = (f16*)(ws + 10ull * NBE);         // 1.5 MB
    char*  tail = ws + 10ull * NBE + (2u << 20);
    float* Lg   = (float*)(tail);                   // 4097
    float* Wfin = (float*)(tail + 16512);           // 4096
    int*   sLo  = (int*)(tail + 16512 + 16384);     // 128

    prep_kernel<<<2241, 256, 0, stream>>>(X, WQ, WK, WV, Xf, WT, Lg, Wfin, sLo);
    qkv_mfma<<<1536, 256, 0, stream>>>(Xf, WT, bQ, bK, bV, Qf, Kf, KT, VT);
    attn_mfma<<<512, 512, 0, stream>>>(Qf, Kf, VT, Lg, sLo, out);
    sfinal_mfma<<<dim3(8, 4, Bsz), 256, 0, stream>>>(KT, VT, Lg, Wfin, S_out);
}